// Round 26
// baseline (120.337 us; speedup 1.0000x reference)
//
#include <hip/hip_runtime.h>

// Conv2d 5x5, C=3, O=1, stride 1, pad 2, N=256, H=W=224, +bias.
// R26 = R24 (42.3us best) + nontemporal stores + per-block channel rotation.
//   R25 post-mortem: barrier-free = 44.4 (10 vs 16 waves/CU + stage ampl.);
//   all schedule shapes land 42-50 -> R24 structure is the local optimum.
//   Remaining levers cut WORK, not schedule:
//   1) __builtin_nontemporal_store for output: write-once lines bypass L2
//      -> hot input rows stay resident -> FETCH_SIZE should drop.
//   2) channel order rotated by band%3: desyncs stage bursts across the 4
//      resident blocks/CU (accum order change is numerically irrelevant).
// Kept from R24: grid 3584 (8*448 XCD swizzle), 1 band/block, 3 literal
// phases, BAND=16, RST=232 (232%32=8), +4-dword shift, LDS-resident x-pads,
// 7-wide x 2-tall full-lane mapping, stage via gl_lds16 (wave-uniform dest,
// lane<56), 4 blocks/CU, no launch_bounds min-arg, no setprio.

namespace {

constexpr int Hc = 224, Wc = 224, Cc = 3;
constexpr int HW = Hc * Wc;
constexpr int CHW = Cc * HW;
constexpr int BAND = 16;              // output rows per band (= per block)
constexpr int SROWS = BAND + 4;       // 20 staged rows per (band, channel)
constexpr int RST = 232;              // LDS row stride (dwords); 232%32 = 8
constexpr int BUFD = SROWS * RST;     // 4640 dwords = 18560 B per buffer
constexpr int SPI = Hc / BAND;        // 14 bands (strips) per image
constexpr int BLK = 256;

__device__ __forceinline__ void gl_lds16(const float* g, float* l) {
  __builtin_amdgcn_global_load_lds(
      (const __attribute__((address_space(1))) void*)g,
      (__attribute__((address_space(3))) void*)l, 16, 0, 0);
}

__global__ __launch_bounds__(BLK) void conv5x5_r26(
    const float* __restrict__ x, const float* __restrict__ wl,
    const float* __restrict__ bptr, float* __restrict__ out) {
  __shared__ __align__(16) float sm[2 * BUFD];   // 37120 B

  const int tid = threadIdx.x;
  const int lane = tid & 63;
  const int wv = tid >> 6;

  // Bijective XCD swizzle: 3584 = 8 * 448.
  const int cpx = gridDim.x >> 3;
  const int bid = (blockIdx.x & 7) * cpx + (blockIdx.x >> 3);
  const int n = bid / SPI;                 // image
  const int band = bid % SPI;              // band index (16 rows)
  const int crot = band % 3;               // channel rotation for this block

  // Weights: wave-uniform, compile-time offsets -> SGPRs.
  float w[Cc][5][5];
#pragma unroll
  for (int c = 0; c < Cc; ++c)
#pragma unroll
    for (int i = 0; i < 25; ++i) w[c][i / 5][i % 5] = wl[c * 25 + i];
  const float bias = bptr[0];

  const float* xn = x + (size_t)n * CHW;
  float* outn = out + (size_t)n * HW;

  // Compute roles: 256 threads = 32 col-groups (7 outputs wide) x 8
  // row-groups (2 rows). Window base = LDS dword 7g+2 (global dword j lives
  // at LDS j+4; window = global 7g-2..7g+8 = LDS 7g+2..7g+12).
  const int g = tid & 31;
  const int tg = tid >> 5;
  const int rdo = g * 7 + 2;

  float acc[2][7];                         // 2 rows x 7 cols, static indexed
#pragma unroll
  for (int r = 0; r < 2; ++r)
#pragma unroll
    for (int c = 0; c < 7; ++c) acc[r][c] = 0.f;

  // ---- one-time x-pad zeroing: dwords {2,3,228,229} of all 40 rows ----
  // (staging writes only dwords 4..227; window max dword = 7*31+2+10 = 229)
  if (tid < 160) {
    const int buf = tid / 80;
    const int rem = tid % 80;
    const int row = rem >> 2;
    const int j = rem & 3;
    const int dw = (j < 2) ? (2 + j) : (226 + j);   // 2,3,228,229
    sm[buf * BUFD + row * RST + dw] = 0.f;
  }

  // Stage phase P (literal): 20 rows of channel (P+crot)%3, band `band`,
  // into buffer P&1. Wave wv owns rows {wv, wv+4, wv+8, wv+12, wv+16}.
  // LDS dest is the wave-uniform row base (+4-dword shift); HW adds lane*16
  // (lanes >= 56 masked; row data = dwords 4..227). OOB rows (y pad) zero-
  // filled via vector store (lanes < 56 -> pads untouched).
#define STAGE_P(P)                                                            \
  do {                                                                        \
    const int chs_ = ((P) + crot) % 3;                                        \
    const float* gch_ = xn + (size_t)chs_ * HW;                               \
    float* smb_ = sm + ((P) & 1) * BUFD;                                      \
    _Pragma("unroll") for (int i_ = 0; i_ < 5; ++i_) {                        \
      const int r_ = wv + 4 * i_;                                             \
      const int gy_ = band * BAND - 2 + r_;                                   \
      float* ld_ = smb_ + r_ * RST + 4;                                       \
      if (gy_ >= 0 && gy_ < Hc) {                                             \
        if (lane < 56)                                                        \
          gl_lds16(gch_ + (size_t)gy_ * Wc + lane * 4, ld_);                  \
      } else {                                                                \
        if (lane < 56)                                                        \
          *(float4*)(ld_ + lane * 4) = make_float4(0.f, 0.f, 0.f, 0.f);       \
      }                                                                       \
    }                                                                         \
  } while (0)

  // Compute phase P (literal) from buffer P&1, channel (P+crot)%3 (runtime
  // per block, wave-uniform -> w[chs_] rows become SGPR-selected; weights
  // are all resident in SGPRs so the select is scalar and cheap).
  // Thread reads LDS rows tg*2 + jj, jj=0..5; output row r taps ky = jj-r.
  // Window = raw 11-dword read (x-pads are real zeros in LDS; no masks).
#define COMPUTE_P(P)                                                          \
  do {                                                                        \
    const int chs_ = ((P) + crot) % 3;                                        \
    const float* smb_ = sm + ((P) & 1) * BUFD;                                \
    _Pragma("unroll") for (int jj_ = 0; jj_ < 6; ++jj_) {                     \
      const float* rp_ = smb_ + (tg * 2 + jj_) * RST + rdo;                   \
      float win_[11];                                                         \
      _Pragma("unroll") for (int j_ = 0; j_ < 11; ++j_) win_[j_] = rp_[j_];   \
      _Pragma("unroll") for (int r_ = 0; r_ < 2; ++r_) {                      \
        if (r_ <= jj_ && jj_ - r_ <= 4) {                                     \
          _Pragma("unroll") for (int kx_ = 0; kx_ < 5; ++kx_) {               \
            const float wv_ = w[chs_][jj_ - r_][kx_];                         \
            _Pragma("unroll") for (int c_ = 0; c_ < 7; ++c_) {                \
              acc[r_][c_] = fmaf(win_[c_ + kx_], wv_, acc[r_][c_]);           \
            }                                                                 \
          }                                                                   \
        }                                                                     \
      }                                                                       \
    }                                                                         \
    if ((P) == 2) {                                                           \
      _Pragma("unroll") for (int r_ = 0; r_ < 2; ++r_) {                      \
        const int gy_ = band * BAND + tg * 2 + r_;                            \
        float* op_ = outn + (size_t)gy_ * Wc + g * 7;                         \
        _Pragma("unroll") for (int c_ = 0; c_ < 7; ++c_)                      \
            __builtin_nontemporal_store(acc[r_][c_] + bias, op_ + c_);        \
      }                                                                       \
    }                                                                         \
  } while (0)

  // ---- pipeline: stage(P+1) flies under compute(P); 3 barriers total ----
  STAGE_P(0);
  __syncthreads(); STAGE_P(1); COMPUTE_P(0);
  __syncthreads(); STAGE_P(2); COMPUTE_P(1);
  __syncthreads();             COMPUTE_P(2);

#undef STAGE_P
#undef COMPUTE_P
}

}  // namespace

extern "C" void kernel_launch(void* const* d_in, const int* in_sizes, int n_in,
                              void* d_out, int out_size, void* d_ws, size_t ws_size,
                              hipStream_t stream) {
  const float* x  = (const float*)d_in[0];   // [N,3,224,224] f32
  const float* wl = (const float*)d_in[1];   // [1,75] f32
  const float* b  = (const float*)d_in[2];   // [1] f32
  float* out = (float*)d_out;                // [N,224,224] f32

  const int N = out_size / HW;               // 256
  const int nblk = N * SPI;                  // 3584 = 8 * 448

  conv5x5_r26<<<nblk, BLK, 0, stream>>>(x, wl, b, out);
}

// Round 27
// 42.521 us; speedup vs baseline: 2.8301x; 2.8301x over previous
//
#include <hip/hip_runtime.h>

// Conv2d 5x5, C=3, O=1, stride 1, pad 2, N=256, H=W=224, +bias.
// R27 = exact revert to R24 (42.3us session best).
//   R26 post-mortem: nontemporal SCALAR stores bypass L2 write-combining ->
//   WRITE_SIZE 50->349 MB (7x amplification); runtime-indexed w[chs_] broke
//   compile-time weight selection (rule #20). Both falsified; reverted.
// Final structure (validated across R15-R26 sweeps):
//   - channel-phase double-buffered LDS pipeline, 3 literal phases, stage
//     ch P+1 (global_load_lds, wave-uniform dest, lane<56) under compute ch P
//   - BAND=16 rows/block, 20 staged rows (RST=232 dw, 232%32=8 bank rotation,
//     +4-dword shift), 2x18560 B LDS -> 4 blocks/CU x 4 waves = 16 waves/CU
//   - 7-wide x 2-tall full-lane mapping (256 = 32 col-groups x 8 row-groups);
//     window = raw 11-dword LDS read; x-pads are LDS-resident zeros
//   - grid 3584 = 8*448, bijective XCD swizzle; no launch_bounds min-arg
// Falsified alternatives: launch-bounds cap (R9: spill), sched_barrier (R8),
// rolled pressure (R10), XOR chunk swizzle (R16), BAND=32 (R18/R19),
// persistent chains + setprio (R23), barrier-free vmcnt (R25), nt stores +
// channel rotation (R26).

namespace {

constexpr int Hc = 224, Wc = 224, Cc = 3;
constexpr int HW = Hc * Wc;
constexpr int CHW = Cc * HW;
constexpr int BAND = 16;              // output rows per band (= per block)
constexpr int SROWS = BAND + 4;       // 20 staged rows per (band, channel)
constexpr int RST = 232;              // LDS row stride (dwords); 232%32 = 8
constexpr int BUFD = SROWS * RST;     // 4640 dwords = 18560 B per buffer
constexpr int SPI = Hc / BAND;        // 14 bands (strips) per image
constexpr int BLK = 256;

__device__ __forceinline__ void gl_lds16(const float* g, float* l) {
  __builtin_amdgcn_global_load_lds(
      (const __attribute__((address_space(1))) void*)g,
      (__attribute__((address_space(3))) void*)l, 16, 0, 0);
}

__global__ __launch_bounds__(BLK) void conv5x5_r27(
    const float* __restrict__ x, const float* __restrict__ wl,
    const float* __restrict__ bptr, float* __restrict__ out) {
  __shared__ __align__(16) float sm[2 * BUFD];   // 37120 B

  const int tid = threadIdx.x;
  const int lane = tid & 63;
  const int wv = tid >> 6;

  // Bijective XCD swizzle: 3584 = 8 * 448.
  const int cpx = gridDim.x >> 3;
  const int bid = (blockIdx.x & 7) * cpx + (blockIdx.x >> 3);
  const int n = bid / SPI;                 // image
  const int band = bid % SPI;              // band index (16 rows)

  // Weights: wave-uniform, compile-time offsets -> SGPRs.
  float w[Cc][5][5];
#pragma unroll
  for (int c = 0; c < Cc; ++c)
#pragma unroll
    for (int i = 0; i < 25; ++i) w[c][i / 5][i % 5] = wl[c * 25 + i];
  const float bias = bptr[0];

  const float* xn = x + (size_t)n * CHW;
  float* outn = out + (size_t)n * HW;

  // Compute roles: 256 threads = 32 col-groups (7 outputs wide) x 8
  // row-groups (2 rows). Window base = LDS dword 7g+2 (global dword j lives
  // at LDS j+4; window = global 7g-2..7g+8 = LDS 7g+2..7g+12).
  const int g = tid & 31;
  const int tg = tid >> 5;
  const int rdo = g * 7 + 2;

  float acc[2][7];                         // 2 rows x 7 cols, static indexed

  // ---- one-time x-pad zeroing: dwords {2,3,228,229} of all 40 rows ----
  // (staging writes only dwords 4..227; window max dword = 7*31+2+10 = 229;
  //  g=0 reads dwords 2,3 = zeros, g=31 reads 228,229 = zeros)
  if (tid < 160) {
    const int buf = tid / 80;
    const int rem = tid % 80;
    const int row = rem >> 2;
    const int j = rem & 3;
    const int dw = (j < 2) ? (2 + j) : (226 + j);   // 2,3,228,229
    sm[buf * BUFD + row * RST + dw] = 0.f;
  }

  // Stage phase P (literal): 20 rows of channel P, band `band`, into buffer
  // P&1. Wave wv owns rows {wv, wv+4, wv+8, wv+12, wv+16}. LDS dest is the
  // wave-uniform row base (+4-dword shift); HW adds lane*16 (lanes >= 56
  // masked; row data = dwords 4..227). OOB rows (y pad: band 0 r<2, band 13
  // r>=18) zero-filled via vector store (lanes < 56 -> pads untouched).
#define STAGE_P(P)                                                            \
  do {                                                                        \
    const float* gch_ = xn + (size_t)(P) * HW;                                \
    float* smb_ = sm + ((P) & 1) * BUFD;                                      \
    _Pragma("unroll") for (int i_ = 0; i_ < 5; ++i_) {                        \
      const int r_ = wv + 4 * i_;                                             \
      const int gy_ = band * BAND - 2 + r_;                                   \
      float* ld_ = smb_ + r_ * RST + 4;                                       \
      if (gy_ >= 0 && gy_ < Hc) {                                             \
        if (lane < 56)                                                        \
          gl_lds16(gch_ + (size_t)gy_ * Wc + lane * 4, ld_);                  \
      } else {                                                                \
        if (lane < 56)                                                        \
          *(float4*)(ld_ + lane * 4) = make_float4(0.f, 0.f, 0.f, 0.f);       \
      }                                                                       \
    }                                                                         \
  } while (0)

  // Compute phase P (literal) from buffer P&1. Thread reads LDS rows
  // tg*2 + jj, jj=0..5; output row r (0..1) taps jj = r..r+4 (ky = jj-r).
  // Window = raw 11-dword read (x-pads are real zeros in LDS; no masks).
#define COMPUTE_P(P)                                                          \
  do {                                                                        \
    constexpr int ch_ = (P);                                                  \
    const float* smb_ = sm + ((P) & 1) * BUFD;                                \
    if (ch_ == 0) {                                                           \
      _Pragma("unroll") for (int r_ = 0; r_ < 2; ++r_)                        \
          _Pragma("unroll") for (int c_ = 0; c_ < 7; ++c_)                    \
              acc[r_][c_] = 0.f;                                              \
    }                                                                         \
    _Pragma("unroll") for (int jj_ = 0; jj_ < 6; ++jj_) {                     \
      const float* rp_ = smb_ + (tg * 2 + jj_) * RST + rdo;                   \
      float win_[11];                                                         \
      _Pragma("unroll") for (int j_ = 0; j_ < 11; ++j_) win_[j_] = rp_[j_];   \
      _Pragma("unroll") for (int r_ = 0; r_ < 2; ++r_) {                      \
        if (r_ <= jj_ && jj_ - r_ <= 4) {                                     \
          _Pragma("unroll") for (int kx_ = 0; kx_ < 5; ++kx_) {               \
            const float wv_ = w[ch_][jj_ - r_][kx_];                          \
            _Pragma("unroll") for (int c_ = 0; c_ < 7; ++c_) {                \
              acc[r_][c_] = fmaf(win_[c_ + kx_], wv_, acc[r_][c_]);           \
            }                                                                 \
          }                                                                   \
        }                                                                     \
      }                                                                       \
    }                                                                         \
    if (ch_ == 2) {                                                           \
      _Pragma("unroll") for (int r_ = 0; r_ < 2; ++r_) {                      \
        const int gy_ = band * BAND + tg * 2 + r_;                            \
        float* op_ = outn + (size_t)gy_ * Wc + g * 7;                         \
        _Pragma("unroll") for (int c_ = 0; c_ < 7; ++c_)                      \
            op_[c_] = acc[r_][c_] + bias;                                     \
      }                                                                       \
    }                                                                         \
  } while (0)

  // ---- pipeline: stage(P+1) flies under compute(P); 3 barriers total ----
  STAGE_P(0);
  __syncthreads(); STAGE_P(1); COMPUTE_P(0);
  __syncthreads(); STAGE_P(2); COMPUTE_P(1);
  __syncthreads();             COMPUTE_P(2);

#undef STAGE_P
#undef COMPUTE_P
}

}  // namespace

extern "C" void kernel_launch(void* const* d_in, const int* in_sizes, int n_in,
                              void* d_out, int out_size, void* d_ws, size_t ws_size,
                              hipStream_t stream) {
  const float* x  = (const float*)d_in[0];   // [N,3,224,224] f32
  const float* wl = (const float*)d_in[1];   // [1,75] f32
  const float* b  = (const float*)d_in[2];   // [1] f32
  float* out = (float*)d_out;                // [N,224,224] f32

  const int N = out_size / HW;               // 256
  const int nblk = N * SPI;                  // 3584 = 8 * 448

  conv5x5_r27<<<nblk, BLK, 0, stream>>>(x, wl, b, out);
}